// Round 1
// baseline (322.203 us; speedup 1.0000x reference)
//
#include <hip/hip_runtime.h>
#include <hip/hip_bf16.h>

// MeanPooling as batched GEMM: out[b,n,h] = (sum_s map[b,n,s]*doc[b,s,h]) / len[b,n]
// B=8, N=512 (M), S=4096 (K), H=1024 (N-dim). All fp32 in/out.
// Strategy: bf16 MFMA (16x16x32) with on-the-fly fp32->bf16 conversion,
// 128x128 tiles, BK=32, 4 waves/block (64x64 per wave), double-buffered LDS,
// padded LDS stride (40 elems = 20 banks) for conflict-free ds_read_b128.

typedef __bf16 bf16x8 __attribute__((ext_vector_type(8)));
typedef float  f32x4  __attribute__((ext_vector_type(4)));

#define MFMA16(a, b, c) __builtin_amdgcn_mfma_f32_16x16x32_bf16(a, b, c, 0, 0, 0)

constexpr int Bsz = 8;
constexpr int Nn  = 512;   // nodes (M)
constexpr int Ss  = 4096;  // seq   (K)
constexpr int Hh  = 1024;  // hidden(N)

constexpr int BM = 128, BN = 128, BK = 32;
constexpr int LDK = BK + 8;  // 40 elems -> 80 B row stride (20 banks, 16B aligned)
constexpr int NT = Ss / BK;  // 128 K-steps

__global__ __launch_bounds__(256, 1)
void mean_pool_gemm(const float* __restrict__ doc,   // [B,S,H]
                    const float* __restrict__ map,   // [B,N,S]
                    const float* __restrict__ len,   // [B,N]
                    float* __restrict__ out)         // [B,N,H]
{
    __shared__ __align__(16) __bf16 As[2][BM * LDK];
    __shared__ __align__(16) __bf16 Bs[2][BN * LDK];

    const int blk = blockIdx.x;          // 0..255
    const int b   = blk >> 5;            // batch
    const int mt  = (blk >> 3) & 3;      // m-tile (nodes)
    const int ht  = blk & 7;             // h-tile
    const int n0  = mt * BM;
    const int h0  = ht * BN;

    const int tid  = threadIdx.x;
    const int wave = tid >> 6;
    const int lane = tid & 63;
    const int wr   = wave >> 1;          // wave row (0/1)
    const int wc   = wave & 1;           // wave col (0/1)
    const int l15  = lane & 15;
    const int l4   = lane >> 4;

    const float* Ab = map + (size_t)b * Nn * Ss + (size_t)n0 * Ss;  // A rows n0..n0+127, K-contig
    const float* Bb = doc + (size_t)b * Ss * Hh + h0;               // B rows s, cols h0..h0+127

    // A staging: thread covers row ra, 16 consecutive k at offset ka
    const int ra = tid >> 1;
    const int ka = (tid & 1) * 16;
    // B staging: thread covers column hb, k-blocks {kb0, kb0+2} of 8
    const int hb  = tid & 127;
    const int kb0 = tid >> 7;  // 0 or 1

    f32x4 aR[4];
    float bR[2][8];
    f32x4 acc[4][4] = {};

    // ---- prologue: load + cvt + write tile 0 into buf 0
    {
        const float* ap = Ab + (size_t)ra * Ss + ka;
        #pragma unroll
        for (int i = 0; i < 4; i++) aR[i] = *(const f32x4*)(ap + i * 4);
        #pragma unroll
        for (int tt = 0; tt < 2; tt++) {
            const float* bp = Bb + (size_t)((kb0 + tt * 2) * 8) * Hh + hb;
            #pragma unroll
            for (int j = 0; j < 8; j++) bR[tt][j] = bp[(size_t)j * Hh];
        }
        bf16x8 v0, v1;
        #pragma unroll
        for (int i = 0; i < 8; i++) {
            v0[i] = (__bf16)aR[i >> 2][i & 3];
            v1[i] = (__bf16)aR[2 + (i >> 2)][i & 3];
        }
        *(bf16x8*)&As[0][ra * LDK + ka]     = v0;
        *(bf16x8*)&As[0][ra * LDK + ka + 8] = v1;
        #pragma unroll
        for (int tt = 0; tt < 2; tt++) {
            bf16x8 w;
            #pragma unroll
            for (int j = 0; j < 8; j++) w[j] = (__bf16)bR[tt][j];
            *(bf16x8*)&Bs[0][hb * LDK + (kb0 + tt * 2) * 8] = w;
        }
    }
    __syncthreads();

    int cur = 0;
    for (int t = 0; t < NT; ++t) {
        // issue next-tile global loads early (latency hides under compute)
        if (t + 1 < NT) {
            const int s0 = (t + 1) * BK;
            const float* ap = Ab + (size_t)ra * Ss + s0 + ka;
            #pragma unroll
            for (int i = 0; i < 4; i++) aR[i] = *(const f32x4*)(ap + i * 4);
            #pragma unroll
            for (int tt = 0; tt < 2; tt++) {
                const float* bp = Bb + (size_t)(s0 + (kb0 + tt * 2) * 8) * Hh + hb;
                #pragma unroll
                for (int j = 0; j < 8; j++) bR[tt][j] = bp[(size_t)j * Hh];
            }
        }

        // compute from buf[cur]
        {
            bf16x8 aF[4], bF[4];
            #pragma unroll
            for (int m = 0; m < 4; m++)
                aF[m] = *(const bf16x8*)&As[cur][(wr * 64 + m * 16 + l15) * LDK + l4 * 8];
            #pragma unroll
            for (int n = 0; n < 4; n++)
                bF[n] = *(const bf16x8*)&Bs[cur][(wc * 64 + n * 16 + l15) * LDK + l4 * 8];
            #pragma unroll
            for (int m = 0; m < 4; m++)
                #pragma unroll
                for (int n = 0; n < 4; n++)
                    acc[m][n] = MFMA16(aF[m], bF[n], acc[m][n]);
        }

        if (t + 1 < NT) {
            __syncthreads();  // all waves done reading buf[cur^1] (their t-1 compute)
            bf16x8 v0, v1;
            #pragma unroll
            for (int i = 0; i < 8; i++) {
                v0[i] = (__bf16)aR[i >> 2][i & 3];
                v1[i] = (__bf16)aR[2 + (i >> 2)][i & 3];
            }
            *(bf16x8*)&As[cur ^ 1][ra * LDK + ka]     = v0;
            *(bf16x8*)&As[cur ^ 1][ra * LDK + ka + 8] = v1;
            #pragma unroll
            for (int tt = 0; tt < 2; tt++) {
                bf16x8 w;
                #pragma unroll
                for (int j = 0; j < 8; j++) w[j] = (__bf16)bR[tt][j];
                *(bf16x8*)&Bs[cur ^ 1][hb * LDK + (kb0 + tt * 2) * 8] = w;
            }
            __syncthreads();  // writes visible before next compute
            cur ^= 1;
        }
    }

    // ---- epilogue: divide by nodes_len, store
    // C/D layout (16x16): col = lane&15, row = (lane>>4)*4 + j   [m89-verified]
    const float* lenb = len + b * Nn + n0 + wr * 64;
    float* ob = out + (size_t)b * Nn * Hh + (size_t)(n0 + wr * 64) * Hh + h0 + wc * 64;
    #pragma unroll
    for (int m = 0; m < 4; m++) {
        float inv[4];
        #pragma unroll
        for (int j = 0; j < 4; j++) inv[j] = 1.0f / lenb[m * 16 + l4 * 4 + j];
        #pragma unroll
        for (int n = 0; n < 4; n++) {
            #pragma unroll
            for (int j = 0; j < 4; j++) {
                const int row = m * 16 + l4 * 4 + j;
                ob[(size_t)row * Hh + n * 16 + l15] = acc[m][n][j] * inv[j];
            }
        }
    }
}

extern "C" void kernel_launch(void* const* d_in, const int* in_sizes, int n_in,
                              void* d_out, int out_size, void* d_ws, size_t ws_size,
                              hipStream_t stream) {
    const float* doc = (const float*)d_in[0];  // [B,S,H]
    const float* map = (const float*)d_in[1];  // [B,N,S]
    const float* len = (const float*)d_in[2];  // [B,N]
    float* out = (float*)d_out;                // [B,N,H]

    dim3 grid(Bsz * (Nn / BM) * (Hh / BN));    // 8*4*8 = 256
    dim3 block(256);
    hipLaunchKernelGGL(mean_pool_gemm, grid, block, 0, stream, doc, map, len, out);
}

// Round 2
// 316.943 us; speedup vs baseline: 1.0166x; 1.0166x over previous
//
#include <hip/hip_runtime.h>
#include <hip/hip_bf16.h>

// MeanPooling as batched GEMM: out[b,n,h] = (sum_s map[b,n,s]*doc[b,s,h]) / len[b,n]
// B=8, N=512 (M), S=4096 (K), H=1024 (N-dim). All fp32 in/out.
// R2: latency-bound fix — 64x64 tiles, 1024 blocks (4/CU, 16 waves/CU),
// XCD swizzle (each XCD owns one batch). bf16 MFMA 16x16x32, BK=32,
// double-buffered LDS, padded LDK=40 (2-way max on reads, free per m136).

typedef __bf16 bf16x8 __attribute__((ext_vector_type(8)));
typedef float  f32x4  __attribute__((ext_vector_type(4)));

#define MFMA16(a, b, c) __builtin_amdgcn_mfma_f32_16x16x32_bf16(a, b, c, 0, 0, 0)

constexpr int Bsz = 8;
constexpr int Nn  = 512;   // nodes (M)
constexpr int Ss  = 4096;  // seq   (K)
constexpr int Hh  = 1024;  // hidden(N)

constexpr int BM = 64, BN = 64, BK = 32;
constexpr int LDK = BK + 8;  // 40 elems -> 80 B row stride
constexpr int NT = Ss / BK;  // 128 K-steps
constexpr int NWG = Bsz * (Nn / BM) * (Hh / BN);  // 8*8*16 = 1024

__global__ __launch_bounds__(256, 4)
void mean_pool_gemm(const float* __restrict__ doc,   // [B,S,H]
                    const float* __restrict__ map,   // [B,N,S]
                    const float* __restrict__ len,   // [B,N]
                    float* __restrict__ out)         // [B,N,H]
{
    __shared__ __align__(16) __bf16 As[2][BM * LDK];  // 5 KB each buf
    __shared__ __align__(16) __bf16 Bs[2][BN * LDK];

    // XCD-aware swizzle: 1024 % 8 == 0, simple bijective form.
    // XCD x gets contiguous blocks x*128..x*128+127 == exactly batch x.
    const int blk = (blockIdx.x & 7) * (NWG / 8) + (blockIdx.x >> 3);

    const int b   = blk >> 7;            // batch (0..7)
    const int rem = blk & 127;
    const int mt  = rem >> 4;            // m-tile (0..7)
    const int ht  = rem & 15;            // h-tile (0..15)
    const int n0  = mt * BM;
    const int h0  = ht * BN;

    const int tid  = threadIdx.x;
    const int wave = tid >> 6;
    const int lane = tid & 63;
    const int wr   = wave >> 1;          // wave row (0/1)
    const int wc   = wave & 1;           // wave col (0/1)
    const int l15  = lane & 15;
    const int l4   = lane >> 4;

    const float* Ab = map + (size_t)b * Nn * Ss + (size_t)n0 * Ss;  // rows K-contig
    const float* Bb = doc + (size_t)b * Ss * Hh + h0;               // rows s, cols h0..h0+63

    // A staging: thread -> row ra (0..63), k-offset ka in {0,8,16,24}
    const int ra = tid >> 2;
    const int ka = (tid & 3) * 8;
    // B staging: thread -> col hbb (0..63), k-block kb (0..3) of 8
    const int hbb = tid & 63;
    const int kb  = tid >> 6;

    f32x4 aR[2];
    float bR[8];
    f32x4 acc[2][2] = {};

    // ---- prologue: tile 0 -> buf 0
    {
        const float* ap = Ab + (size_t)ra * Ss + ka;
        aR[0] = *(const f32x4*)(ap);
        aR[1] = *(const f32x4*)(ap + 4);
        const float* bp = Bb + (size_t)(kb * 8) * Hh + hbb;
        #pragma unroll
        for (int j = 0; j < 8; j++) bR[j] = bp[(size_t)j * Hh];

        bf16x8 va, vb;
        #pragma unroll
        for (int i = 0; i < 8; i++) {
            va[i] = (__bf16)aR[i >> 2][i & 3];
            vb[i] = (__bf16)bR[i];
        }
        *(bf16x8*)&As[0][ra * LDK + ka]      = va;
        *(bf16x8*)&Bs[0][hbb * LDK + kb * 8] = vb;
    }
    __syncthreads();

    int cur = 0;
    for (int t = 0; t < NT; ++t) {
        // issue next-tile global loads early
        if (t + 1 < NT) {
            const int s0 = (t + 1) * BK;
            const float* ap = Ab + (size_t)ra * Ss + s0 + ka;
            aR[0] = *(const f32x4*)(ap);
            aR[1] = *(const f32x4*)(ap + 4);
            const float* bp = Bb + (size_t)(s0 + kb * 8) * Hh + hbb;
            #pragma unroll
            for (int j = 0; j < 8; j++) bR[j] = bp[(size_t)j * Hh];
        }

        // compute from buf[cur]
        {
            bf16x8 aF[2], bF[2];
            #pragma unroll
            for (int m = 0; m < 2; m++)
                aF[m] = *(const bf16x8*)&As[cur][(wr * 32 + m * 16 + l15) * LDK + l4 * 8];
            #pragma unroll
            for (int n = 0; n < 2; n++)
                bF[n] = *(const bf16x8*)&Bs[cur][(wc * 32 + n * 16 + l15) * LDK + l4 * 8];
            #pragma unroll
            for (int m = 0; m < 2; m++)
                #pragma unroll
                for (int n = 0; n < 2; n++)
                    acc[m][n] = MFMA16(aF[m], bF[n], acc[m][n]);
        }

        if (t + 1 < NT) {
            __syncthreads();  // all waves done reading buf[cur^1]
            bf16x8 va, vb;
            #pragma unroll
            for (int i = 0; i < 8; i++) {
                va[i] = (__bf16)aR[i >> 2][i & 3];
                vb[i] = (__bf16)bR[i];
            }
            *(bf16x8*)&As[cur ^ 1][ra * LDK + ka]      = va;
            *(bf16x8*)&Bs[cur ^ 1][hbb * LDK + kb * 8] = vb;
            __syncthreads();  // writes visible before next compute
            cur ^= 1;
        }
    }

    // ---- epilogue: divide by nodes_len, store
    // C/D layout (16x16): col = lane&15, row = (lane>>4)*4 + j   [m89-verified]
    const float* lenb = len + b * Nn + n0 + wr * 32;
    float* ob = out + (size_t)b * Nn * Hh + (size_t)(n0 + wr * 32) * Hh + h0 + wc * 32;
    #pragma unroll
    for (int m = 0; m < 2; m++) {
        float inv[4];
        #pragma unroll
        for (int j = 0; j < 4; j++) inv[j] = 1.0f / lenb[m * 16 + l4 * 4 + j];
        #pragma unroll
        for (int n = 0; n < 2; n++) {
            #pragma unroll
            for (int j = 0; j < 4; j++) {
                const int row = m * 16 + l4 * 4 + j;
                ob[(size_t)row * Hh + n * 16 + l15] = acc[m][n][j] * inv[j];
            }
        }
    }
}

extern "C" void kernel_launch(void* const* d_in, const int* in_sizes, int n_in,
                              void* d_out, int out_size, void* d_ws, size_t ws_size,
                              hipStream_t stream) {
    const float* doc = (const float*)d_in[0];  // [B,S,H]
    const float* map = (const float*)d_in[1];  // [B,N,S]
    const float* len = (const float*)d_in[2];  // [B,N]
    float* out = (float*)d_out;                // [B,N,H]

    dim3 grid(NWG);     // 1024 blocks = 4 per CU
    dim3 block(256);
    hipLaunchKernelGGL(mean_pool_gemm, grid, block, 0, stream, doc, map, len, out);
}